// Round 2
// baseline (84.759 us; speedup 1.0000x reference)
//
#include <hip/hip_runtime.h>
#include <math.h>

#define TABN 2048
#define EPB_BLK 8        // LUT entries per block (4 waves, 2 entries/wave)
#define ROWS_PER_WAVE 8
#define BATCH 4
#define D 1000
#define DV4 250          // 1000 floats = 250 float4; row stride 4000B is 16B-aligned

// ---------------- LUT kernel: tabulate f(s) = sigmoid(MLP(s)) over s in [-1,1] ----------
__global__ __launch_bounds__(256) void lut_kernel(
    const float* __restrict__ w1, const float* __restrict__ b1,
    const float* __restrict__ w2, const float* __restrict__ b2,
    const float* __restrict__ w3, const float* __restrict__ b3,
    const float* __restrict__ w4, const float* __restrict__ b4,
    float* __restrict__ lut)
{
    __shared__ float h1[EPB_BLK][512];
    __shared__ float h2s[EPB_BLK][64];
    const int tid  = threadIdx.x;
    const int lane = tid & 63;
    const int wid  = tid >> 6;               // 0..3
    const int e0 = blockIdx.x * EPB_BLK;

    // layer 1: 1 -> 512, all 256 threads over j, entries unrolled
    for (int j = tid; j < 512; j += 256) {
        float wj = w1[j], bj = b1[j];
#pragma unroll
        for (int e = 0; e < EPB_BLK; ++e) {
            float s = -1.0f + 2.0f * (float)(e0 + e) / (float)(TABN - 1);
            float v = fmaf(wj, s, bj);
            h1[e][j] = v > 0.0f ? v : 0.0f;
        }
    }
    __syncthreads();

    // layer 2: 512 -> 64. wave w owns entries 2w, 2w+1; lane = output unit k.
    const int ea = 2 * wid, eb = 2 * wid + 1;
    float acc0 = b2[lane], acc1 = acc0;
#pragma unroll 4
    for (int j = 0; j < 512; ++j) {
        float w = w2[j * 64 + lane];
        acc0 = fmaf(w, h1[ea][j], acc0);
        acc1 = fmaf(w, h1[eb][j], acc1);
    }
    h2s[ea][lane] = acc0 > 0.0f ? acc0 : 0.0f;
    h2s[eb][lane] = acc1 > 0.0f ? acc1 : 0.0f;
    // intra-wave LDS RAW only — no barrier needed (compiler inserts lgkmcnt)

    // layer 3 (64 -> 32) + layer 4 partial: lanes 0..31, m = lane
    float p0 = 0.0f, p1 = 0.0f;
    if (lane < 32) {
        float b3m = b3[lane];
        float w4m = w4[lane];
        float a0 = b3m, a1 = b3m;
#pragma unroll 4
        for (int k = 0; k < 64; ++k) {
            float wv = w3[k * 32 + lane];
            a0 = fmaf(wv, h2s[ea][k], a0);
            a1 = fmaf(wv, h2s[eb][k], a1);
        }
        p0 = (a0 > 0.0f ? a0 : 0.0f) * w4m;
        p1 = (a1 > 0.0f ? a1 : 0.0f) * w4m;
    }
#pragma unroll
    for (int off = 32; off >= 1; off >>= 1) {
        p0 += __shfl_down(p0, off, 64);
        p1 += __shfl_down(p1, off, 64);
    }
    if (lane == 0) {
        float b4v = b4[0];
        float z0 = p0 + b4v, z1 = p1 + b4v;
        lut[e0 + ea] = 1.0f / (1.0f + expf(-z0));
        lut[e0 + eb] = 1.0f / (1.0f + expf(-z1));
    }
}

// ---------------- main kernel: cosine sim + LUT lerp ----------------
__device__ __forceinline__ float dot4(float4 a, float4 b, float acc) {
    acc = fmaf(a.x, b.x, acc);
    acc = fmaf(a.y, b.y, acc);
    acc = fmaf(a.z, b.z, acc);
    acc = fmaf(a.w, b.w, acc);
    return acc;
}

__global__ __launch_bounds__(256) void sim_kernel(
    const float* __restrict__ query, const float* __restrict__ emb,
    const float* __restrict__ lut, float* __restrict__ out, int N)
{
    const int lane = threadIdx.x & 63;
    const int wave = blockIdx.x * (blockDim.x >> 6) + (threadIdx.x >> 6);

    const float4 zero4 = make_float4(0.f, 0.f, 0.f, 0.f);
    const float4* q4 = (const float4*)query;
    float4 q0 = q4[lane];
    float4 q1 = q4[lane + 64];
    float4 q2 = q4[lane + 128];
    float4 q3 = (lane < DV4 - 192) ? q4[lane + 192] : zero4;

    float nq = 0.f;
    nq = dot4(q0, q0, nq); nq = dot4(q1, q1, nq);
    nq = dot4(q2, q2, nq); nq = dot4(q3, q3, nq);
#pragma unroll
    for (int off = 32; off >= 1; off >>= 1) nq += __shfl_xor(nq, off, 64);
    const float qn = sqrtf(nq);

    const int base0 = wave * ROWS_PER_WAVE;
    if (base0 >= N) return;

#pragma unroll
    for (int b = 0; b < ROWS_PER_WAVE / BATCH; ++b) {
        const int base = base0 + b * BATCH;
        float4 A[BATCH][4];
#pragma unroll
        for (int r = 0; r < BATCH; ++r) {
            const float4* e4 = (const float4*)(emb + (size_t)(base + r) * D);
            A[r][0] = e4[lane];
            A[r][1] = e4[lane + 64];
            A[r][2] = e4[lane + 128];
            A[r][3] = (lane < DV4 - 192) ? e4[lane + 192] : zero4;
        }
        float dt[BATCH], nn[BATCH];
#pragma unroll
        for (int r = 0; r < BATCH; ++r) {
            float d = 0.f, n = 0.f;
            d = dot4(A[r][0], q0, d); n = dot4(A[r][0], A[r][0], n);
            d = dot4(A[r][1], q1, d); n = dot4(A[r][1], A[r][1], n);
            d = dot4(A[r][2], q2, d); n = dot4(A[r][2], A[r][2], n);
            d = dot4(A[r][3], q3, d); n = dot4(A[r][3], A[r][3], n);
            dt[r] = d; nn[r] = n;
        }
        // 8 independent butterfly chains, interleaved per level
#pragma unroll
        for (int off = 32; off >= 1; off >>= 1) {
#pragma unroll
            for (int r = 0; r < BATCH; ++r) {
                dt[r] += __shfl_xor(dt[r], off, 64);
                nn[r] += __shfl_xor(nn[r], off, 64);
            }
        }
        if (lane == 0) {
            float4 res;
#pragma unroll
            for (int r = 0; r < BATCH; ++r) {
                float sim = dt[r] / fmaxf(sqrtf(nn[r]) * qn, 1e-8f);
                float t = (sim + 1.0f) * (0.5f * (float)(TABN - 1));
                t = fminf(fmaxf(t, 0.0f), (float)(TABN - 1));
                int i0 = (int)t;
                if (i0 > TABN - 2) i0 = TABN - 2;
                float fr = t - (float)i0;
                float v0 = lut[i0], v1 = lut[i0 + 1];
                (&res.x)[r] = fmaf(v1 - v0, fr, v0);
            }
            *(float4*)(out + base) = res;
        }
    }
}

extern "C" void kernel_launch(void* const* d_in, const int* in_sizes, int n_in,
                              void* d_out, int out_size, void* d_ws, size_t ws_size,
                              hipStream_t stream) {
    const float* query = (const float*)d_in[0];
    const float* emb   = (const float*)d_in[1];
    const float* w1    = (const float*)d_in[2];
    const float* b1    = (const float*)d_in[3];
    const float* w2    = (const float*)d_in[4];
    const float* b2    = (const float*)d_in[5];
    const float* w3    = (const float*)d_in[6];
    const float* b3    = (const float*)d_in[7];
    const float* w4    = (const float*)d_in[8];
    const float* b4    = (const float*)d_in[9];
    float* lut = (float*)d_ws;
    float* out = (float*)d_out;
    const int N = in_sizes[1] / D;   // 65536

    lut_kernel<<<TABN / EPB_BLK, 256, 0, stream>>>(w1, b1, w2, b2, w3, b3, w4, b4, lut);

    const int waves = (N + ROWS_PER_WAVE - 1) / ROWS_PER_WAVE;
    const int blocks = (waves + 3) / 4;      // 4 waves (256 threads) per block
    sim_kernel<<<blocks, 256, 0, stream>>>(query, emb, lut, out, N);
}